// Round 1
// baseline (121.766 us; speedup 1.0000x reference)
//
#include <hip/hip_runtime.h>

#define IMG_H 512
#define IMG_W 512
#define N_IMG 32
#define ROWS  4                    // output rows per wave-band (was 8): 2x wave count
#define BANDS (IMG_H / ROWS)       // 128 bands per image
#define ITERS (ROWS + 8)           // 12 row-slides per band
#define NPIX  (32.0f * 512.0f * 512.0f)

// Load 8 consecutive cols of I and normalized T from row r (zeros if r out of range).
__device__ __forceinline__ void load8(const float* __restrict__ ip,
                                      const float* __restrict__ tp,
                                      int r, int c0, float* I, float* T) {
    if (r >= 0 && r < IMG_H) {
        const float* irow = ip + (ptrdiff_t)r * IMG_W + c0;
        const float* trow = tp + (ptrdiff_t)r * IMG_W + c0;
        float4 a = *(const float4*)(irow);
        float4 b = *(const float4*)(irow + 4);
        float4 c = *(const float4*)(trow);
        float4 d = *(const float4*)(trow + 4);
        I[0]=a.x; I[1]=a.y; I[2]=a.z; I[3]=a.w;
        I[4]=b.x; I[5]=b.y; I[6]=b.z; I[7]=b.w;
        T[0]=fmaf(c.x,0.5f,0.5f); T[1]=fmaf(c.y,0.5f,0.5f);
        T[2]=fmaf(c.z,0.5f,0.5f); T[3]=fmaf(c.w,0.5f,0.5f);
        T[4]=fmaf(d.x,0.5f,0.5f); T[5]=fmaf(d.y,0.5f,0.5f);
        T[6]=fmaf(d.z,0.5f,0.5f); T[7]=fmaf(d.w,0.5f,0.5f);
    } else {
        #pragma unroll
        for (int j = 0; j < 8; ++j) { I[j] = 0.0f; T[j] = 0.0f; }
    }
}

// 9-tap horizontal sliding sums, halo via cross-lane shuffles (no LDS, no bank
// conflicts). Left halo = lane-1's o[4..7]; right halo = lane+1's o[0..3].
// nf = lane!=0 (left image edge -> zero pad), nl = lane!=63 (right edge).
__device__ __forceinline__ void hsum8_shfl(const float* o, float* h, bool nf, bool nl) {
    float Lx = __shfl_up(o[4], 1, 64);
    float Ly = __shfl_up(o[5], 1, 64);
    float Lz = __shfl_up(o[6], 1, 64);
    float Lw = __shfl_up(o[7], 1, 64);
    float Rx = __shfl_down(o[0], 1, 64);
    float Ry = __shfl_down(o[1], 1, 64);
    float Rz = __shfl_down(o[2], 1, 64);
    float Rw = __shfl_down(o[3], 1, 64);
    Lx = nf ? Lx : 0.0f;  Ly = nf ? Ly : 0.0f;
    Lz = nf ? Lz : 0.0f;  Lw = nf ? Lw : 0.0f;
    Rx = nl ? Rx : 0.0f;  Ry = nl ? Ry : 0.0f;
    Rz = nl ? Rz : 0.0f;  Rw = nl ? Rw : 0.0f;

    float s = ((Lx + Ly) + (Lz + Lw)) + ((o[0] + o[1]) + (o[2] + o[3])) + o[4];
    h[0] = s;
    s += o[5] - Lx;  h[1] = s;
    s += o[6] - Ly;  h[2] = s;
    s += o[7] - Lz;  h[3] = s;
    s += Rx   - Lw;  h[4] = s;
    s += Ry   - o[0]; h[5] = s;
    s += Rz   - o[1]; h[6] = s;
    s += Rw   - o[2]; h[7] = s;
}

__device__ __forceinline__ float cc_of(float sI, float sT, float sII, float sTT, float sIT) {
    const float inv81 = 1.0f / 81.0f;
    float u     = sI * inv81;
    float w     = sT * inv81;
    float cross = fmaf(-u, sT, sIT);
    float iv    = fmaf(-u, sI, sII);
    float tv    = fmaf(-w, sT, sTT);
    float den   = fmaf(tv, iv, 1e-5f);
    return cross * cross * __builtin_amdgcn_rcpf(den);
}

__global__ __launch_bounds__(256)
void cc_loss_kernel(const float* __restrict__ in, const float* __restrict__ tg,
                    float* __restrict__ out) {
    __shared__ float red[4];

    const int t    = threadIdx.x;
    const int w    = t >> 6;
    const int lane = t & 63;

    const int gband = blockIdx.x * 4 + w;      // 0..4095
    const int b     = gband >> 7;              // image (128 bands each)
    const int band  = gband & (BANDS - 1);
    const int r0    = band * ROWS;
    const size_t base = (size_t)b * (IMG_H * IMG_W);
    const float* ip = in + base;
    const float* tp = tg + base;
    const int c0    = lane * 8;                // own image cols c0..c0+7
    const bool nf   = (lane != 0);
    const bool nl   = (lane != 63);

    float vI[8] = {}, vT[8] = {}, vII[8] = {}, vTT[8] = {}, vIT[8] = {};
    float acc = 0.0f;

    float pLI[8], pLT[8], pQI[8], pQT[8];      // current iter: leading + trailing rows
    float nLI[8], nLT[8], nQI[8], nQT[8];      // prefetched next iter

    load8(ip, tp, r0 - 4, c0, pLI, pLT);       // leading row for it=0
    #pragma unroll
    for (int j = 0; j < 8; ++j) { pQI[j] = 0.0f; pQT[j] = 0.0f; }

    for (int it = 0; it < ITERS; ++it) {
        // ---- prefetch next iteration's rows (consumed after ~full iteration) ----
        if (it + 1 < ITERS) {
            load8(ip, tp, r0 - 3 + it, c0, nLI, nLT);                    // next leading
            const int tr = r0 + it - 12;                                 // next trailing
            load8(ip, tp, (it >= 8) ? tr : -1, c0, nQI, nQT);            // active from it+1>=9
        }

        // ---- vertical slide: 8 own cols, 5 arrays ----
        #pragma unroll
        for (int j = 0; j < 8; ++j) {
            float dI = pLI[j] - pQI[j], aI = pLI[j] + pQI[j];
            float dT = pLT[j] - pQT[j], aT = pLT[j] + pQT[j];
            vI[j]  += dI;
            vT[j]  += dT;
            vII[j]  = fmaf(dI, aI, vII[j]);
            vTT[j]  = fmaf(dT, aT, vTT[j]);
            float m = pQI[j] * pQT[j];
            vIT[j]  = fmaf(pLI[j], pLT[j], vIT[j] - m);
        }

        // ---- H phase: pure shuffle halo exchange, no LDS ----
        if (it >= 8) {
            float h0[8], h1[8], h2[8], h3[8], h4[8];
            hsum8_shfl(vI,  h0, nf, nl);
            hsum8_shfl(vT,  h1, nf, nl);
            hsum8_shfl(vII, h2, nf, nl);
            hsum8_shfl(vTT, h3, nf, nl);
            hsum8_shfl(vIT, h4, nf, nl);
            #pragma unroll
            for (int j = 0; j < 8; ++j)
                acc += cc_of(h0[j], h1[j], h2[j], h3[j], h4[j]);
        }

        // ---- rotate prefetch ----
        #pragma unroll
        for (int j = 0; j < 8; ++j) {
            pLI[j] = nLI[j]; pLT[j] = nLT[j];
            pQI[j] = nQI[j]; pQT[j] = nQT[j];
        }
    }

    // ---- reduction: wave shuffle, one barrier per block, one atomic ----
    #pragma unroll
    for (int off = 32; off > 0; off >>= 1) acc += __shfl_down(acc, off, 64);
    if (lane == 0) red[w] = acc;
    __syncthreads();
    if (t == 0)
        atomicAdd(out, (red[0] + red[1] + red[2] + red[3]) * (-1.0f / NPIX));
}

extern "C" void kernel_launch(void* const* d_in, const int* in_sizes, int n_in,
                              void* d_out, int out_size, void* d_ws, size_t ws_size,
                              hipStream_t stream) {
    const float* in = (const float*)d_in[0];
    const float* tg = (const float*)d_in[1];
    float* out = (float*)d_out;

    hipMemsetAsync(out, 0, sizeof(float), stream);
    dim3 grid(N_IMG * BANDS / 4);              // 1024 blocks x 4 wave-bands
    cc_loss_kernel<<<grid, 256, 0, stream>>>(in, tg, out);
}